// Round 3
// baseline (413.065 us; speedup 1.0000x reference)
//
#include <hip/hip_runtime.h>
#include <stdint.h>
#include <stddef.h>

// out[M,N] = clip(x,±6)[M,K] @ (W_i8[N,K]*scale[N])^T + bias[N]
// M=8192, N=4096, K=4096.
// Round 7: two independent barrier domains per CU. 256-thread blocks
// (4 waves, 256x128 tile, 128x64/wave), ring-3 LDS (72 KB) -> 2 blocks/CU.
// The two co-resident blocks drift out of phase, so one block's ds_read
// burst overlaps the other's MFMA cluster (lockstep-barrier serialization
// was the round-5/6 gate: MfmaUtil pinned at 42% = MFMA/(MFMA+LDS) serial).
// No setprio (starves the sibling block's read issue). Counted vmcnt(6).

#define M_DIM 8192
#define N_DIM 4096
#define K_DIM 4096
#define ACT_CLIP 6.0f

#define BM 256
#define BN 128
#define BKI 64                     // i8 K-elements per K-tile (64 B/row)
#define NKT (K_DIM / BKI)          // 64 K-tiles
#define A_BYTES (BM * BKI)         // 16 KB
#define B_BYTES (BN * BKI)         // 8 KB
#define TILE_LDS (A_BYTES + B_BYTES)  // 24 KB
#define RING 3                     // 72 KB per block -> 2 blocks/CU

typedef __attribute__((ext_vector_type(4))) int i32x4;
typedef __attribute__((ext_vector_type(16))) int i32x16;

// async global->LDS, 16B/lane; LDS dest is wave-uniform base + lane*16.
__device__ __forceinline__ void async_load16(const void* g, void* l) {
    __builtin_amdgcn_global_load_lds(
        (const __attribute__((address_space(1))) void*)g,
        (__attribute__((address_space(3))) void*)l, 16, 0, 0);
}

// ---------------------------------------------------------------------------
// Fused prepass: blocks [0, M_DIM) quantize x rows; blocks [M_DIM, ...) pack w.
__global__ __launch_bounds__(256) void prep_kernel(
    const float* __restrict__ x, int8_t* __restrict__ xq,
    float* __restrict__ rowscale,
    const int* __restrict__ w, int8_t* __restrict__ wq) {
    const int tid = threadIdx.x;
    if (blockIdx.x < M_DIM) {
        const int row = blockIdx.x;
        const float4* xr = (const float4*)(x + (size_t)row * K_DIM);
        float4 v[4];
        float mx = 0.f;
#pragma unroll
        for (int c = 0; c < 4; ++c) {
            float4 a = xr[c * 256 + tid];
            a.x = fminf(ACT_CLIP, fmaxf(-ACT_CLIP, a.x));
            a.y = fminf(ACT_CLIP, fmaxf(-ACT_CLIP, a.y));
            a.z = fminf(ACT_CLIP, fmaxf(-ACT_CLIP, a.z));
            a.w = fminf(ACT_CLIP, fmaxf(-ACT_CLIP, a.w));
            v[c] = a;
            mx = fmaxf(mx, fmaxf(fmaxf(fabsf(a.x), fabsf(a.y)),
                                 fmaxf(fabsf(a.z), fabsf(a.w))));
        }
#pragma unroll
        for (int off = 32; off >= 1; off >>= 1)
            mx = fmaxf(mx, __shfl_xor(mx, off, 64));
        __shared__ float wmax[4];
        if ((tid & 63) == 0) wmax[tid >> 6] = mx;
        __syncthreads();
        mx = fmaxf(fmaxf(wmax[0], wmax[1]), fmaxf(wmax[2], wmax[3]));
        mx = fmaxf(mx, 1e-20f);
        const float inv = 127.f / mx;
        if (tid == 0) rowscale[row] = mx * (1.f / 127.f);
        int* out = (int*)(xq + (size_t)row * K_DIM);
#pragma unroll
        for (int c = 0; c < 4; ++c) {
            int b0 = (int)rintf(v[c].x * inv);
            int b1 = (int)rintf(v[c].y * inv);
            int b2 = (int)rintf(v[c].z * inv);
            int b3 = (int)rintf(v[c].w * inv);
            out[c * 256 + tid] =
                (b0 & 255) | ((b1 & 255) << 8) | ((b2 & 255) << 16) | ((b3 & 255) << 24);
        }
    } else {
        size_t idx = (size_t)(blockIdx.x - M_DIM) * 256 + tid;
        const int4* w4 = (const int4*)w;
        int r[4];
#pragma unroll
        for (int j = 0; j < 4; ++j) {
            int4 a = w4[idx * 4 + j];
            r[j] = (a.x & 255) | ((a.y & 255) << 8) | ((a.z & 255) << 16) |
                   ((a.w & 255) << 24);
        }
        ((int4*)wq)[idx] = make_int4(r[0], r[1], r[2], r[3]);
    }
}

// ---------------------------------------------------------------------------
// GEMM: dot_i32[M,N] = xq[M,K] @ wq[N,K]^T ; out = dot*(rowscale[m]*scale[n])+bias[n]
// 256x128 tile, BK=64, 256 threads = 4 waves (2M x 2N), 128x64 per wave
// (4x2 of 32x32). Ring-3 K-tile pipeline, lead-2.
__global__ __launch_bounds__(256, 2) void gemm_i8_kernel(
    const int8_t* __restrict__ A, const int8_t* __restrict__ Bw,
    const float* __restrict__ rowscale, const float* __restrict__ scale,
    const float* __restrict__ bias, float* __restrict__ out) {
    extern __shared__ __align__(16) int8_t smem[];  // RING * 24 KB

    const int tid = threadIdx.x;
    const int wave = tid >> 6;
    const int lane = tid & 63;
    const int l31 = lane & 31;
    const int hi = lane >> 5;
    const int m0 = blockIdx.y * BM;
    const int n0 = blockIdx.x * BN;
    const int wm = (wave >> 1) * 128;  // wave's A-row base within tile
    const int wn = (wave & 1) * 64;    // wave's B-row base within tile

    // ---- staging setup -----------------------------------------------------
    // A: 1024 slots of 16B (rows 0..255 x 4 chunks); B: 512 slots at +16KB.
    // slot = row*4 + (chunk ^ ((row>>1)&3)).
    const int8_t* ga[4];
    const int8_t* gb[2];
    int lbA[4], lbB[2];
#pragma unroll
    for (int j = 0; j < 4; ++j) {
        const int s = tid + 256 * j;
        const int row = s >> 2;
        const int c = (s & 3) ^ ((row >> 1) & 3);
        ga[j] = A + (size_t)(m0 + row) * K_DIM + c * 16;
        lbA[j] = (wave * 64 + 256 * j) * 16;
    }
#pragma unroll
    for (int j = 0; j < 2; ++j) {
        const int s = tid + 256 * j;
        const int row = s >> 2;
        const int c = (s & 3) ^ ((row >> 1) & 3);
        gb[j] = Bw + (size_t)(n0 + row) * K_DIM + c * 16;
        lbB[j] = A_BYTES + (wave * 64 + 256 * j) * 16;
    }

    auto STAGE = [&](int b) {  // 6 vm-ops per thread
        int8_t* buf = smem + b * TILE_LDS;
#pragma unroll
        for (int j = 0; j < 4; ++j) async_load16(ga[j], buf + lbA[j]);
#pragma unroll
        for (int j = 0; j < 2; ++j) async_load16(gb[j], buf + lbB[j]);
#pragma unroll
        for (int j = 0; j < 4; ++j) ga[j] += BKI;
#pragma unroll
        for (int j = 0; j < 2; ++j) gb[j] += BKI;
    };

    // ---- fragment read offsets (swizzled), relative to buffer base ---------
    const int swz = (l31 >> 1) & 3;
    const int abase = (wm + l31) * 64;
    const int bbase = A_BYTES + (wn + l31) * 64;
    int koff[2];
#pragma unroll
    for (int ks = 0; ks < 2; ++ks) koff[ks] = ((ks * 2 + hi) ^ swz) * 16;

    i32x16 acc[4][2] = {};

    // ---- prologue: fill pipeline 2 deep, certify tile 0 --------------------
    STAGE(0);
    STAGE(1);
    asm volatile("s_waitcnt vmcnt(6)" ::: "memory");  // tile0's 6 ops done
    asm volatile("s_barrier" ::: "memory");

    // ---- main loop: stage(t+2); read; mfma; certify t+1; barrier -----------
    int cur = 0, stg = 2;
    for (int t = 0; t < NKT; ++t) {
        if (t + 2 < NKT) STAGE(stg);

        const int8_t* buf = smem + cur * TILE_LDS;
        i32x4 af[4][2], bf[2][2];
#pragma unroll
        for (int ks = 0; ks < 2; ++ks) {
#pragma unroll
            for (int mt = 0; mt < 4; ++mt)
                af[mt][ks] = *(const i32x4*)(buf + abase + mt * 2048 + koff[ks]);
#pragma unroll
            for (int nt = 0; nt < 2; ++nt)
                bf[nt][ks] = *(const i32x4*)(buf + bbase + nt * 2048 + koff[ks]);
        }
#pragma unroll
        for (int ks = 0; ks < 2; ++ks)
#pragma unroll
            for (int mt = 0; mt < 4; ++mt)
#pragma unroll
                for (int nt = 0; nt < 2; ++nt)
                    acc[mt][nt] = __builtin_amdgcn_mfma_i32_32x32x32_i8(
                        af[mt][ks], bf[nt][ks], acc[mt][nt], 0, 0, 0);

        // certify tile t+1 (its 6 ops are oldest; t+2's 6 stay in flight)
        if (t < NKT - 2) {
            asm volatile("s_waitcnt vmcnt(6)" ::: "memory");
            asm volatile("s_barrier" ::: "memory");
        } else if (t == NKT - 2) {
            asm volatile("s_waitcnt vmcnt(0)" ::: "memory");
            asm volatile("s_barrier" ::: "memory");
        }  // t == NKT-1: no barrier needed, fall to epilogue
        cur = (cur == 2) ? 0 : cur + 1;
        stg = (stg == 2) ? 0 : stg + 1;
    }

    // ---- epilogue: C/D layout col=lane&31, row=(reg&3)+8*(reg>>2)+4*hi -----
    const int ccol = l31;
#pragma unroll
    for (int mt = 0; mt < 4; ++mt) {
        const int gmb = m0 + wm + mt * 32;
        float rs[16];
#pragma unroll
        for (int r = 0; r < 16; ++r)
            rs[r] = rowscale[gmb + (r & 3) + 4 * hi + 8 * (r >> 2)];
#pragma unroll
        for (int nt = 0; nt < 2; ++nt) {
            const int gn = n0 + wn + nt * 32 + ccol;
            const float sc = scale[gn];
            const float bi = bias[gn];
            float* op = out + (size_t)gmb * N_DIM + gn;
#pragma unroll
            for (int r = 0; r < 16; ++r) {
                const int grow = (r & 3) + 4 * hi + 8 * (r >> 2);
                op[(size_t)grow * N_DIM] =
                    fmaf((float)acc[mt][nt][r], rs[r] * sc, bi);
            }
        }
    }
}

// ---------------------------------------------------------------------------
extern "C" void kernel_launch(void* const* d_in, const int* in_sizes, int n_in,
                              void* d_out, int out_size, void* d_ws, size_t ws_size,
                              hipStream_t stream) {
    const float* x = (const float*)d_in[0];
    const int* w_i8 = (const int*)d_in[1];
    const float* w_scale = (const float*)d_in[2];
    const float* bias = (const float*)d_in[3];
    float* out = (float*)d_out;

    int8_t* xq = (int8_t*)d_ws;                                   // 33.5 MB
    int8_t* wq = (int8_t*)d_ws + (size_t)M_DIM * K_DIM;           // 16.8 MB
    float* rowscale = (float*)((int8_t*)d_ws + (size_t)M_DIM * K_DIM
                               + (size_t)N_DIM * K_DIM);          // 32 KB

    static bool attr_done = false;
    if (!attr_done) {
        hipFuncSetAttribute((const void*)gemm_i8_kernel,
                            hipFuncAttributeMaxDynamicSharedMemorySize,
                            RING * TILE_LDS);
        attr_done = true;
    }

    const int pack_blocks = (int)((size_t)N_DIM * K_DIM / (16 * 256));  // 4096
    prep_kernel<<<M_DIM + pack_blocks, 256, 0, stream>>>(x, xq, rowscale, w_i8, wq);

    dim3 grid(N_DIM / BN, M_DIM / BM);  // (32, 32) = 1024 blocks, 2/CU resident
    gemm_i8_kernel<<<grid, 256, RING * TILE_LDS, stream>>>(
        xq, wq, rowscale, w_scale, bias, out);
}

// Round 4
// 411.148 us; speedup vs baseline: 1.0047x; 1.0047x over previous
//
#include <hip/hip_runtime.h>
#include <stdint.h>
#include <stddef.h>

// out[M,N] = clip(x,±6)[M,K] @ (W_i8[N,K]*scale[N])^T + bias[N]
// M=8192, N=4096, K=4096.
// Round 8: LDS-free GEMM. Rounds 5-7 proved the LDS pipe is the structural
// roofline of staged variants (read+write+conflict cycles > MFMA cycles, and
// in-order read-burst->MFMA-burst phase-locks all waves through the shared
// LDS queue: measured time == LDS+MFMA serial sum across 3 schedules).
// Both operands come from our own prepasses, so the prepasses now emit
// MFMA fragment-tile layout directly:
//   T[blk32][kc][lane] : 1024B chunk = 64 lanes x 16B, lane l = row (l&31),
//   k-bytes [kc*32 + (l>>5)*16, +16).  Fragment loads in the GEMM are then
//   perfectly coalesced global_load_dwordx4 -> VGPR: no LDS, no barriers,
//   no inline asm. Register double-buffer (parity-unrolled), compiler's own
//   counted vmcnt. Prepass tiled writes use an XCD-grouping block swizzle so
//   each 32-row tile's 64B lines assemble within one XCD's L2.

#define M_DIM 8192
#define N_DIM 4096
#define K_DIM 4096
#define ACT_CLIP 6.0f

#define BM 256
#define BN 128
#define BKI 64                  // i8 K per tile-iter: 2 kc-chunks of 32
#define NKT (K_DIM / BKI)       // 64
#define BLK_STRIDE (128 * 1024) // bytes per 32-row stripe: 128 kc x 1024B

typedef __attribute__((ext_vector_type(4))) int i32x4;
typedef __attribute__((ext_vector_type(16))) int i32x16;

// ---------------------------------------------------------------------------
// Fused prepass. Blocks [0, M_DIM): quantize one x-row into tiled xq.
// Blocks [M_DIM, M_DIM+N_DIM): pack one w-row into tiled wq.
// Block->row swizzle groups the 32 rows of each tile onto one XCD (bid%8
// heuristic) so partial 16B line-writes assemble in a single L2.
__global__ __launch_bounds__(256) void prep_kernel(
    const float* __restrict__ x, int8_t* __restrict__ xq,
    float* __restrict__ rowscale,
    const int* __restrict__ w, int8_t* __restrict__ wq) {
    const int tid = threadIdx.x;
    if (blockIdx.x < M_DIM) {
        const int g = blockIdx.x >> 8, i = blockIdx.x & 255;
        const int row = g * 256 + (i & 7) * 32 + (i >> 3);
        // thread owns k-bytes [tid*16, tid*16+16): 4 consecutive float4s
        const float4* xr = (const float4*)(x + (size_t)row * K_DIM);
        float4 v[4];
        float mx = 0.f;
#pragma unroll
        for (int c = 0; c < 4; ++c) {
            float4 a = xr[tid * 4 + c];
            a.x = fminf(ACT_CLIP, fmaxf(-ACT_CLIP, a.x));
            a.y = fminf(ACT_CLIP, fmaxf(-ACT_CLIP, a.y));
            a.z = fminf(ACT_CLIP, fmaxf(-ACT_CLIP, a.z));
            a.w = fminf(ACT_CLIP, fmaxf(-ACT_CLIP, a.w));
            v[c] = a;
            mx = fmaxf(mx, fmaxf(fmaxf(fabsf(a.x), fabsf(a.y)),
                                 fmaxf(fabsf(a.z), fabsf(a.w))));
        }
#pragma unroll
        for (int off = 32; off >= 1; off >>= 1)
            mx = fmaxf(mx, __shfl_xor(mx, off, 64));
        __shared__ float wmax[4];
        if ((tid & 63) == 0) wmax[tid >> 6] = mx;
        __syncthreads();
        mx = fmaxf(fmaxf(wmax[0], wmax[1]), fmaxf(wmax[2], wmax[3]));
        mx = fmaxf(mx, 1e-20f);
        const float inv = 127.f / mx;
        if (tid == 0) rowscale[row] = mx * (1.f / 127.f);
        int bo[4];
#pragma unroll
        for (int c = 0; c < 4; ++c) {
            int b0 = (int)rintf(v[c].x * inv);
            int b1 = (int)rintf(v[c].y * inv);
            int b2 = (int)rintf(v[c].z * inv);
            int b3 = (int)rintf(v[c].w * inv);
            bo[c] = (b0 & 255) | ((b1 & 255) << 8) | ((b2 & 255) << 16) |
                    ((b3 & 255) << 24);
        }
        // tiled dest: kc = tid>>1, hi = tid&1
        int8_t* dst = xq + ((size_t)(row >> 5) * 128 + (tid >> 1)) * 1024 +
                      (row & 31) * 16 + (tid & 1) * 512;
        *(int4*)dst = make_int4(bo[0], bo[1], bo[2], bo[3]);
    } else {
        const int pb = blockIdx.x - M_DIM;
        const int g = pb >> 8, i = pb & 255;
        const int n = g * 256 + (i & 7) * 32 + (i >> 3);
        // thread owns k-bytes [tid*16, +16) of weight row n
        const int4* w4 = (const int4*)(w + (size_t)n * K_DIM);
        int bo[4];
#pragma unroll
        for (int j = 0; j < 4; ++j) {
            int4 a = w4[tid * 4 + j];
            bo[j] = (a.x & 255) | ((a.y & 255) << 8) | ((a.z & 255) << 16) |
                    ((a.w & 255) << 24);
        }
        int8_t* dst = wq + ((size_t)(n >> 5) * 128 + (tid >> 1)) * 1024 +
                      (n & 31) * 16 + (tid & 1) * 512;
        *(int4*)dst = make_int4(bo[0], bo[1], bo[2], bo[3]);
    }
}

// ---------------------------------------------------------------------------
// LDS-free GEMM: 256x128 tile, 256 threads = 4 waves (2M x 2N), 128x64/wave
// (4x2 of 32x32x32 i8). Register double-buffer, prefetch one K-tile ahead.
__global__ __launch_bounds__(256, 2) void gemm_i8_kernel(
    const int8_t* __restrict__ At, const int8_t* __restrict__ Bt,
    const float* __restrict__ rowscale, const float* __restrict__ scale,
    const float* __restrict__ bias, float* __restrict__ out) {
    const int tid = threadIdx.x;
    const int wave = tid >> 6;
    const int lane = tid & 63;
    const int l31 = lane & 31;
    const int hi = lane >> 5;
    const int m0 = blockIdx.y * BM;
    const int n0 = blockIdx.x * BN;
    const int wm = (wave >> 1) * 128;  // wave's M base within tile
    const int wn = (wave & 1) * 64;    // wave's N base within tile

    // fragment stream pointers: one per 32-row stripe, bumped 2048 B / K-tile
    const int8_t* pa[4];
    const int8_t* pb[2];
#pragma unroll
    for (int mt = 0; mt < 4; ++mt)
        pa[mt] = At + (size_t)(((m0 + wm) >> 5) + mt) * BLK_STRIDE + lane * 16;
#pragma unroll
    for (int nt = 0; nt < 2; ++nt)
        pb[nt] = Bt + (size_t)(((n0 + wn) >> 5) + nt) * BLK_STRIDE + lane * 16;

    i32x4 aX[8], bX[4], aY[8], bY[4];  // [mt*2+ks] / [nt*2+ks]
    i32x16 acc[4][2] = {};

#define LOADT(af, bf)                                                  \
    do {                                                               \
        _Pragma("unroll") for (int mt = 0; mt < 4; ++mt) {             \
            af[mt * 2 + 0] = *(const i32x4*)(pa[mt]);                  \
            af[mt * 2 + 1] = *(const i32x4*)(pa[mt] + 1024);           \
        }                                                              \
        _Pragma("unroll") for (int nt = 0; nt < 2; ++nt) {             \
            bf[nt * 2 + 0] = *(const i32x4*)(pb[nt]);                  \
            bf[nt * 2 + 1] = *(const i32x4*)(pb[nt] + 1024);           \
        }                                                              \
        _Pragma("unroll") for (int mt = 0; mt < 4; ++mt) pa[mt] += 2048; \
        _Pragma("unroll") for (int nt = 0; nt < 2; ++nt) pb[nt] += 2048; \
    } while (0)

#define MFMAT(af, bf)                                                  \
    do {                                                               \
        _Pragma("unroll") for (int ks = 0; ks < 2; ++ks)               \
            _Pragma("unroll") for (int mt = 0; mt < 4; ++mt)           \
                _Pragma("unroll") for (int nt = 0; nt < 2; ++nt)       \
                    acc[mt][nt] = __builtin_amdgcn_mfma_i32_32x32x32_i8( \
                        af[mt * 2 + ks], bf[nt * 2 + ks], acc[mt][nt], \
                        0, 0, 0);                                      \
    } while (0)

    LOADT(aX, bX);  // tile 0
    for (int t = 0; t < NKT - 2; t += 2) {
        LOADT(aY, bY);   // prefetch t+1 (flies under the MFMAs below)
        MFMAT(aX, bX);   // tile t
        LOADT(aX, bX);   // prefetch t+2
        MFMAT(aY, bY);   // tile t+1
    }
    LOADT(aY, bY);       // tile NKT-1
    MFMAT(aX, bX);       // tile NKT-2
    MFMAT(aY, bY);       // tile NKT-1

#undef LOADT
#undef MFMAT

    // epilogue: C/D layout col=lane&31, row=(reg&3)+8*(reg>>2)+4*hi
    const int ccol = l31;
#pragma unroll
    for (int mt = 0; mt < 4; ++mt) {
        const int gmb = m0 + wm + mt * 32;
        float rs[16];
#pragma unroll
        for (int r = 0; r < 16; ++r)
            rs[r] = rowscale[gmb + (r & 3) + 4 * hi + 8 * (r >> 2)];
#pragma unroll
        for (int nt = 0; nt < 2; ++nt) {
            const int gn = n0 + wn + nt * 32 + ccol;
            const float sc = scale[gn];
            const float bi = bias[gn];
            float* op = out + (size_t)gmb * N_DIM + gn;
#pragma unroll
            for (int r = 0; r < 16; ++r) {
                const int grow = (r & 3) + 4 * hi + 8 * (r >> 2);
                op[(size_t)grow * N_DIM] =
                    fmaf((float)acc[mt][nt][r], rs[r] * sc, bi);
            }
        }
    }
}

// ---------------------------------------------------------------------------
extern "C" void kernel_launch(void* const* d_in, const int* in_sizes, int n_in,
                              void* d_out, int out_size, void* d_ws, size_t ws_size,
                              hipStream_t stream) {
    const float* x = (const float*)d_in[0];
    const int* w_i8 = (const int*)d_in[1];
    const float* w_scale = (const float*)d_in[2];
    const float* bias = (const float*)d_in[3];
    float* out = (float*)d_out;

    int8_t* xq = (int8_t*)d_ws;                                   // 33.5 MB (tiled)
    int8_t* wq = (int8_t*)d_ws + (size_t)M_DIM * K_DIM;           // 16.8 MB (tiled)
    float* rowscale = (float*)((int8_t*)d_ws + (size_t)M_DIM * K_DIM
                               + (size_t)N_DIM * K_DIM);          // 32 KB

    prep_kernel<<<M_DIM + N_DIM, 256, 0, stream>>>(x, xq, rowscale, w_i8, wq);

    dim3 grid(N_DIM / BN, M_DIM / BM);  // (32, 32) = 1024 blocks, 2/CU resident
    gemm_i8_kernel<<<grid, 256, 0, stream>>>(
        xq, wq, rowscale, w_scale, bias, out);
}

// Round 5
// 400.775 us; speedup vs baseline: 1.0307x; 1.0259x over previous
//
#include <hip/hip_runtime.h>
#include <stdint.h>
#include <stddef.h>

// out[M,N] = clip(x,±6)[M,K] @ (W_i8[N,K]*scale[N])^T + bias[N]
// M=8192, N=4096, K=4096.
// Round 9: faithful m201-style 8-phase-per-2-K-tiles schedule, ported to i8.
// 256x256 tile, 8 waves, BK=128 (128-byte LDS rows -> 3-bit XOR swizzle
// c' = c ^ (row&7), conflict-free in 8-lane groups; the old 64B rows could
// never beat 4-way). 4 phases per K-tile: {6 ds_read; 4 gload_lds; barrier;
// lgkm(0); setprio(1); 8 MFMA; setprio(0); barrier}. vmcnt(0) only at tile
// boundary (loads were issued 2+ phases earlier -> near-zero wait).
// Rounds 5-8 proved coarse read-burst/MFMA-burst schedules pin at 36-42%
// regardless of sourcing; fine phase interleave is the measured fix (m201).

#define M_DIM 8192
#define N_DIM 4096
#define K_DIM 4096
#define ACT_CLIP 6.0f

#define BM 256
#define BN 256
#define BKB 128                // i8 K-elements per K-tile (128 B rows)
#define NKT (K_DIM / BKB)      // 32
#define B_OFF 32768            // B region offset within a buffer
#define BUF_BYTES 65536        // A 32KB + B 32KB
// LDS slot layout per region: slot s (16B) -> row = s>>3, chunk c' = s&7,
// holding global chunk c = c' ^ (row&7).

typedef __attribute__((ext_vector_type(4))) int i32x4;
typedef __attribute__((ext_vector_type(16))) int i32x16;

// async global->LDS, 16B/lane; LDS dest is wave-uniform base + lane*16.
__device__ __forceinline__ void async_load16(const void* g, void* l) {
    __builtin_amdgcn_global_load_lds(
        (const __attribute__((address_space(1))) void*)g,
        (__attribute__((address_space(3))) void*)l, 16, 0, 0);
}

// ---------------------------------------------------------------------------
// Fused prepass: blocks [0, M_DIM) quantize x rows; blocks [M_DIM, ...) pack w.
// Linear row-major outputs (the GEMM swizzles on its global source addrs).
__global__ __launch_bounds__(256) void prep_kernel(
    const float* __restrict__ x, int8_t* __restrict__ xq,
    float* __restrict__ rowscale,
    const int* __restrict__ w, int8_t* __restrict__ wq) {
    const int tid = threadIdx.x;
    if (blockIdx.x < M_DIM) {
        const int row = blockIdx.x;
        const float4* xr = (const float4*)(x + (size_t)row * K_DIM);
        float4 v[4];
        float mx = 0.f;
#pragma unroll
        for (int c = 0; c < 4; ++c) {
            float4 a = xr[c * 256 + tid];
            a.x = fminf(ACT_CLIP, fmaxf(-ACT_CLIP, a.x));
            a.y = fminf(ACT_CLIP, fmaxf(-ACT_CLIP, a.y));
            a.z = fminf(ACT_CLIP, fmaxf(-ACT_CLIP, a.z));
            a.w = fminf(ACT_CLIP, fmaxf(-ACT_CLIP, a.w));
            v[c] = a;
            mx = fmaxf(mx, fmaxf(fmaxf(fabsf(a.x), fabsf(a.y)),
                                 fmaxf(fabsf(a.z), fabsf(a.w))));
        }
#pragma unroll
        for (int off = 32; off >= 1; off >>= 1)
            mx = fmaxf(mx, __shfl_xor(mx, off, 64));
        __shared__ float wmax[4];
        if ((tid & 63) == 0) wmax[tid >> 6] = mx;
        __syncthreads();
        mx = fmaxf(fmaxf(wmax[0], wmax[1]), fmaxf(wmax[2], wmax[3]));
        mx = fmaxf(mx, 1e-20f);
        const float inv = 127.f / mx;
        if (tid == 0) rowscale[row] = mx * (1.f / 127.f);
        int* out = (int*)(xq + (size_t)row * K_DIM);
#pragma unroll
        for (int c = 0; c < 4; ++c) {
            int b0 = (int)rintf(v[c].x * inv);
            int b1 = (int)rintf(v[c].y * inv);
            int b2 = (int)rintf(v[c].z * inv);
            int b3 = (int)rintf(v[c].w * inv);
            out[c * 256 + tid] =
                (b0 & 255) | ((b1 & 255) << 8) | ((b2 & 255) << 16) | ((b3 & 255) << 24);
        }
    } else {
        size_t idx = (size_t)(blockIdx.x - M_DIM) * 256 + tid;
        const int4* w4 = (const int4*)w;
        int r[4];
#pragma unroll
        for (int j = 0; j < 4; ++j) {
            int4 a = w4[idx * 4 + j];
            r[j] = (a.x & 255) | ((a.y & 255) << 8) | ((a.z & 255) << 16) |
                   ((a.w & 255) << 24);
        }
        ((int4*)wq)[idx] = make_int4(r[0], r[1], r[2], r[3]);
    }
}

// ---------------------------------------------------------------------------
// GEMM: dot_i32[M,N] = xq[M,K] @ wq[N,K]^T ; out = dot*(rowscale[m]*scale[n])+bias[n]
// 256x256 tile, BK=128, 512 threads = 8 waves (2M x 4N), 128x64/wave
// (4x2 of 32x32x32 i8). Double-buffered LDS, 4-phase interleave per K-tile.
__global__ __launch_bounds__(512, 2) void gemm_i8_kernel(
    const int8_t* __restrict__ A, const int8_t* __restrict__ Bw,
    const float* __restrict__ rowscale, const float* __restrict__ scale,
    const float* __restrict__ bias, float* __restrict__ out) {
    extern __shared__ __align__(16) int8_t smem[];  // 2 * 64 KB

    const int tid = threadIdx.x;
    const int wave = tid >> 6;
    const int lane = tid & 63;
    const int l31 = lane & 31;
    const int hi = lane >> 5;
    const int m0 = blockIdx.y * BM;
    const int n0 = blockIdx.x * BN;
    const int wm = (wave >> 2) * 128;  // wave's A-row base within tile
    const int wn = (wave & 3) * 64;    // wave's B-row base within tile

    // ---- staging setup: thread owns slots s = i*512 + tid, i = 0..3, for
    // both A and B regions. Global source pre-swizzled: c = (s&7) ^ (row&7).
    const int8_t* gsA[4];
    const int8_t* gsB[4];
    int ldA[4], ldB[4];  // wave-uniform LDS byte bases
#pragma unroll
    for (int i = 0; i < 4; ++i) {
        const int s = i * 512 + tid;
        const int row = s >> 3;
        const int c = (s & 7) ^ (row & 7);
        gsA[i] = A + (size_t)(m0 + row) * K_DIM + c * 16;
        gsB[i] = Bw + (size_t)(n0 + row) * K_DIM + c * 16;
        ldA[i] = (i * 512 + wave * 64) * 16;
        ldB[i] = B_OFF + (i * 512 + wave * 64) * 16;
    }

    // ---- fragment read offsets. row&7 == l31&7 (wm, mt*32, wn multiples of 32).
    // addr = row*128 + ((kc*2+hi) ^ (row&7))*16; mt/nt via +4096 immediates.
    const int sw = l31 & 7;
    const int abase = (wm + l31) * BKB;
    const int bbase = B_OFF + (wn + l31) * BKB;
    int koff[4];
#pragma unroll
    for (int kc = 0; kc < 4; ++kc) koff[kc] = ((kc * 2 + hi) ^ sw) * 16;

    i32x16 acc[4][2] = {};

    // ---- prologue: stage tile 0 into buf0, certify ----
#pragma unroll
    for (int i = 0; i < 4; ++i) {
        async_load16(gsA[i], smem + ldA[i]);
        async_load16(gsB[i], smem + ldB[i]);
        gsA[i] += BKB;
        gsB[i] += BKB;
    }
    asm volatile("s_waitcnt vmcnt(0)" ::: "memory");
    __builtin_amdgcn_s_barrier();

    // ---- main loop: 4 phases per K-tile -------------------------------------
    for (int t = 0; t < NKT; ++t) {
        const int8_t* buf = smem + (size_t)(t & 1) * BUF_BYTES;
        int8_t* nbuf = smem + (size_t)((t + 1) & 1) * BUF_BYTES;
        const bool more = (t + 1 < NKT);
#pragma unroll
        for (int kc = 0; kc < 4; ++kc) {
            // phase reads: 6 ds_read_b128 (4 A + 2 B fragments for this kc)
            i32x4 af[4], bf[2];
#pragma unroll
            for (int mt = 0; mt < 4; ++mt)
                af[mt] = *(const i32x4*)(buf + abase + mt * 4096 + koff[kc]);
#pragma unroll
            for (int nt = 0; nt < 2; ++nt)
                bf[nt] = *(const i32x4*)(buf + bbase + nt * 4096 + koff[kc]);
            // stage next tile: 4 gload_lds in each of phases 0,1
            if (more && kc < 2) {
#pragma unroll
                for (int i = kc * 2; i < kc * 2 + 2; ++i) {
                    async_load16(gsA[i], nbuf + ldA[i]);
                    async_load16(gsB[i], nbuf + ldB[i]);
                    gsA[i] += BKB;
                    gsB[i] += BKB;
                }
            }
            __builtin_amdgcn_s_barrier();
            asm volatile("s_waitcnt lgkmcnt(0)" ::: "memory");
            __builtin_amdgcn_sched_barrier(0);
            __builtin_amdgcn_s_setprio(1);
#pragma unroll
            for (int mt = 0; mt < 4; ++mt)
#pragma unroll
                for (int nt = 0; nt < 2; ++nt)
                    acc[mt][nt] = __builtin_amdgcn_mfma_i32_32x32x32_i8(
                        af[mt], bf[nt], acc[mt][nt], 0, 0, 0);
            __builtin_amdgcn_s_setprio(0);
            if (kc == 3) {
                // certify next tile's LDS writes (issued >=2 phases ago)
                asm volatile("s_waitcnt vmcnt(0)" ::: "memory");
            }
            __builtin_amdgcn_s_barrier();
        }
    }

    // ---- epilogue: C/D layout col=lane&31, row=(reg&3)+8*(reg>>2)+4*hi -----
    const int ccol = l31;
#pragma unroll
    for (int mt = 0; mt < 4; ++mt) {
        const int gmb = m0 + wm + mt * 32;
        float rs[16];
#pragma unroll
        for (int r = 0; r < 16; ++r)
            rs[r] = rowscale[gmb + (r & 3) + 4 * hi + 8 * (r >> 2)];
#pragma unroll
        for (int nt = 0; nt < 2; ++nt) {
            const int gn = n0 + wn + nt * 32 + ccol;
            const float sc = scale[gn];
            const float bi = bias[gn];
            float* op = out + (size_t)gmb * N_DIM + gn;
#pragma unroll
            for (int r = 0; r < 16; ++r) {
                const int grow = (r & 3) + 4 * hi + 8 * (r >> 2);
                op[(size_t)grow * N_DIM] =
                    fmaf((float)acc[mt][nt][r], rs[r] * sc, bi);
            }
        }
    }
}

// ---------------------------------------------------------------------------
extern "C" void kernel_launch(void* const* d_in, const int* in_sizes, int n_in,
                              void* d_out, int out_size, void* d_ws, size_t ws_size,
                              hipStream_t stream) {
    const float* x = (const float*)d_in[0];
    const int* w_i8 = (const int*)d_in[1];
    const float* w_scale = (const float*)d_in[2];
    const float* bias = (const float*)d_in[3];
    float* out = (float*)d_out;

    int8_t* xq = (int8_t*)d_ws;                                   // 33.5 MB
    int8_t* wq = (int8_t*)d_ws + (size_t)M_DIM * K_DIM;           // 16.8 MB
    float* rowscale = (float*)((int8_t*)d_ws + (size_t)M_DIM * K_DIM
                               + (size_t)N_DIM * K_DIM);          // 32 KB

    static bool attr_done = false;
    if (!attr_done) {
        hipFuncSetAttribute((const void*)gemm_i8_kernel,
                            hipFuncAttributeMaxDynamicSharedMemorySize,
                            2 * BUF_BYTES);
        attr_done = true;
    }

    const int pack_blocks = (int)((size_t)N_DIM * K_DIM / (16 * 256));  // 4096
    prep_kernel<<<M_DIM + pack_blocks, 256, 0, stream>>>(x, xq, rowscale, w_i8, wq);

    dim3 grid(N_DIM / BN, M_DIM / BM);  // (16, 32) = 512 blocks
    gemm_i8_kernel<<<grid, 512, 2 * BUF_BYTES, stream>>>(
        xq, wq, rowscale, w_scale, bias, out);
}